// Round 17
// baseline (98.765 us; speedup 1.0000x reference)
//
#include <hip/hip_runtime.h>
#include <hip/hip_bf16.h>
#include <hip/hip_fp16.h>
#include <math.h>
#include <stdint.h>

#define F_IN  32
#define F_HID 32
#define F_OUT 16
#define NPB     256    // nodes per bucket
#define LOG_NPB 8
#define MAXNB   512    // supports n <= 131072
#define BH      512    // histogram/fill blocks

typedef float floatx2 __attribute__((ext_vector_type(2)));

__device__ inline floatx2 fp8_lo(uint32_t w) {   // 2 fp8 (bytes 0,1) -> 2 f32
    return __builtin_amdgcn_cvt_pk_f32_fp8(w, false);
}
__device__ inline floatx2 fp8_hi(uint32_t w) {   // 2 fp8 (bytes 2,3) -> 2 f32
    return __builtin_amdgcn_cvt_pk_f32_fp8(w, true);
}
__device__ inline uint32_t pack_fp8x4(float a, float b, float c, float d) {
    uint32_t u = __builtin_amdgcn_cvt_pk_fp8_f32(a, b, 0u, false);
    u = __builtin_amdgcn_cvt_pk_fp8_f32(c, d, u, true);
    return u;
}
__device__ inline floatx2 shflx(floatx2 v, int off) {
    floatx2 r;
    r[0] = __shfl_xor(v[0], off);
    r[1] = __shfl_xor(v[1], off);
    return r;
}

__device__ inline float fexp(float x) {           // e^x
    return __builtin_amdgcn_exp2f(x * 1.44269504089f);
}
__device__ inline float ftanh(float x) {          // tanh via exp2+rcp
    x = fminf(fmaxf(x, -15.f), 15.f);
    float t = __builtin_amdgcn_exp2f(x * 2.88539008178f);  // e^(2x)
    return (t - 1.0f) * __builtin_amdgcn_rcpf(t + 1.0f);
}

// ---- pass A: per-block bucket histogram, 8 replicated sub-hists ----
__launch_bounds__(512)
__global__ void k_hist(const int* __restrict__ ei, int ne, int chunk, int nb,
                       int* __restrict__ hist_mat) {
    __shared__ int hist[8][MAXNB];
    int t = threadIdx.x, b = blockIdx.x;
    int rep = t >> 6;  // per-wave sub-hist
    for (int i = t; i < 8 * MAXNB; i += 512) ((int*)hist)[i] = 0;
    __syncthreads();
    long s = (long)b * chunk;
    long e = s + chunk; if (e > ne) e = ne;
    const int* dstp = ei + ne;
    long i = s + (long)t * 4;
    for (; i + 4 <= e; i += 2048) {
        int4 d = *(const int4*)(dstp + i);
        atomicAdd(&hist[rep][d.x >> LOG_NPB], 1);
        atomicAdd(&hist[rep][d.y >> LOG_NPB], 1);
        atomicAdd(&hist[rep][d.z >> LOG_NPB], 1);
        atomicAdd(&hist[rep][d.w >> LOG_NPB], 1);
    }
    if (i < e)
        for (long j = i; j < e; ++j) atomicAdd(&hist[rep][dstp[j] >> LOG_NPB], 1);
    __syncthreads();
    for (int k = t; k < nb; k += 512) {
        int v = 0;
        #pragma unroll
        for (int r = 0; r < 8; ++r) v += hist[r][k];
        hist_mat[(size_t)b * nb + k] = v;
    }
}

// ---- column scan (wave per column): off_mat[b][k] = col-exclusive prefix ----
__launch_bounds__(64)
__global__ void k_colscan(const int* __restrict__ hist_mat, int* __restrict__ off_mat,
                          int* __restrict__ totalG, int nb) {
    int k = blockIdx.x;
    if (k >= nb) return;
    int lane = threadIdx.x;
    int run = 0;
    #pragma unroll
    for (int c = 0; c < BH; c += 64) {
        size_t idx = (size_t)(c + lane) * nb + k;
        int v = hist_mat[idx];
        int inc = v;
        #pragma unroll
        for (int o = 1; o < 64; o <<= 1) {
            int u = __shfl_up(inc, o);
            if (lane >= o) inc += u;
        }
        off_mat[idx] = run + inc - v;
        run += __shfl(inc, 63);
    }
    if (lane == 0) totalG[k] = run;
}

// ---- pass C: in-block boff scan + place edges via LDS cursors ----
__launch_bounds__(512)
__global__ void k_fillc(const int* __restrict__ ei, int ne, int chunk, int nb,
                        const int* __restrict__ off_mat, const int* __restrict__ totalG,
                        int* __restrict__ boff, uint32_t* __restrict__ ebuf) {
    __shared__ int cur[MAXNB];
    __shared__ int sc[512];
    int t = threadIdx.x, b = blockIdx.x;
    int tv = (t < nb) ? totalG[t] : 0;
    sc[t] = tv; __syncthreads();
    for (int o = 1; o < 512; o <<= 1) {
        int u = (t >= o) ? sc[t - o] : 0;
        __syncthreads();
        sc[t] += u;
        __syncthreads();
    }
    int myboff = sc[t] - tv;  // exclusive prefix of totalG at bucket t
    if (t < nb) cur[t] = off_mat[(size_t)b * nb + t] + myboff;
    if (b == 0) {  // publish boff for k_pass2
        if (t < nb) boff[t] = myboff;
        if (t == 0) boff[nb] = ne;
    }
    __syncthreads();
    long s = (long)b * chunk;
    long e = s + chunk; if (e > ne) e = ne;
    const int* srcp = ei;
    const int* dstp = ei + ne;
    long i = s + (long)t * 4;
    for (; i + 4 <= e; i += 2048) {
        int4 sv = *(const int4*)(srcp + i);
        int4 dv = *(const int4*)(dstp + i);
        int p0 = atomicAdd(&cur[dv.x >> LOG_NPB], 1);
        ebuf[p0] = (uint32_t)sv.x | ((uint32_t)(dv.x & (NPB - 1)) << 17);
        int p1 = atomicAdd(&cur[dv.y >> LOG_NPB], 1);
        ebuf[p1] = (uint32_t)sv.y | ((uint32_t)(dv.y & (NPB - 1)) << 17);
        int p2 = atomicAdd(&cur[dv.z >> LOG_NPB], 1);
        ebuf[p2] = (uint32_t)sv.z | ((uint32_t)(dv.z & (NPB - 1)) << 17);
        int p3 = atomicAdd(&cur[dv.w >> LOG_NPB], 1);
        ebuf[p3] = (uint32_t)sv.w | ((uint32_t)(dv.w & (NPB - 1)) << 17);
    }
    if (i < e) {
        for (long j = i; j < e; ++j) {
            int sn = srcp[j], dn = dstp[j];
            int p = atomicAdd(&cur[dn >> LOG_NPB], 1);
            ebuf[p] = (uint32_t)sn | ((uint32_t)(dn & (NPB - 1)) << 17);
        }
    }
}

// ---- pass 2: within-bucket sort -> csr + off_g + dinv + xd = x*dinv (fp8 x4) ----
__launch_bounds__(256)
__global__ void k_pass2(const uint32_t* __restrict__ ebuf, const int* __restrict__ boff,
                        const float* __restrict__ x,
                        int* __restrict__ csr, int* __restrict__ off_g,
                        float* __restrict__ dinv, uint32_t* __restrict__ xd,
                        int n, int nb) {
    __shared__ int hist[NPB], scn[NPB], cur[NPB];
    __shared__ float sdi[NPB];
    int b = blockIdx.x, t = threadIdx.x;
    int base = boff[b], end = boff[b + 1];
    int v0 = b << LOG_NPB;
    hist[t] = 0;
    __syncthreads();
    for (int i = base + t; i < end; i += 256)
        atomicAdd(&hist[(ebuf[i] >> 17) & (NPB - 1)], 1);
    __syncthreads();
    int val = hist[t];
    scn[t] = val; __syncthreads();
    for (int o = 1; o < 256; o <<= 1) {
        int u = (t >= o) ? scn[t - o] : 0;
        __syncthreads();
        scn[t] += u;
        __syncthreads();
    }
    int excl = scn[t] - val + base;
    cur[t] = excl;
    int v = v0 + t;
    float d = 0.f;
    if (v < n) {
        off_g[v] = excl;
        d = rsqrtf((float)(val + 1));  // +1 self-loop
        dinv[v] = d;
    }
    sdi[t] = d;
    if (b == nb - 1 && t == 0) off_g[n] = end;
    if (b == nb - 1 && t < 8) xd[(size_t)n * 8 + t] = 0u;  // zero row for padding
    __syncthreads();
    for (int i = base + t; i < end; i += 256) {
        uint32_t r = ebuf[i];
        int slot = atomicAdd(&cur[(r >> 17) & (NPB - 1)], 1);
        csr[slot] = (int)(r & 0x1FFFF);
    }
    // xd = x * dinv, packed fp8 e4m3 (8 words/node = 32 ch)
    for (int i = t; i < NPB * 8; i += 256) {
        int nl = i >> 3, wp = i & 7;
        int vv = v0 + nl;
        if (vv < n) {
            float4 xx = *(const float4*)(x + (size_t)vv * F_IN + 4 * wp);
            float di = sdi[nl];
            xd[(size_t)vv * 8 + wp] =
                pack_fp8x4(xx.x * di, xx.y * di, xx.z * di, xx.w * di);
        }
    }
}

// ---- agg1: fp8 gather (coalesced csr + virtual self edge), W1->tanh->W2 -> g2 ----
__launch_bounds__(256)
__global__ void k_agg1(const uint32_t* __restrict__ xd, const int* __restrict__ csr,
                       const int* __restrict__ off_g,
                       const float* __restrict__ dinv, const float* __restrict__ b1,
                       const float* __restrict__ W1, const float* __restrict__ W2,
                       uint32_t* __restrict__ g2, int n) {
    __shared__ float W1s[F_IN * F_HID];
    __shared__ float W2s[F_HID * F_OUT];
    __shared__ float sums[8][F_IN + 1];
    __shared__ float hb[8][F_HID + 1];
    int t = threadIdx.x, wv = t >> 6, lane = t & 63;
    ((float4*)W1s)[t] = ((const float4*)W1)[t];               // 1024 floats
    if (t < 128) ((float4*)W2s)[t] = ((const float4*)W2)[t];  // 512 floats
    if (blockIdx.x == 0 && t < 4) g2[(size_t)n * 4 + t] = 0u; // zero row for agg2
    int half = lane >> 5, l = lane & 31;
    int v = blockIdx.x * 8 + wv * 2 + half;
    bool act = v < n;
    int q = l & 3, slot = l >> 2;  // 8 edge slots x 4 lanes x 8B per 32B row
    floatx2 a0 = {0.f, 0.f}, a1 = {0.f, 0.f}, a2 = {0.f, 0.f}, a3 = {0.f, 0.f};
    if (act) {
        int start = off_g[v], cnt = off_g[v + 1] - start;
        const int* cp = csr + start;
        int cl = cp[l];  // ONE coalesced csr load per lane (csr padded +32)
        int hbase = lane & 32;
        int s0 = __shfl(cl, hbase + slot);
        int s1 = __shfl(cl, hbase + slot + 8);
        int s2 = __shfl(cl, hbase + slot + 16);
        int s3 = __shfl(cl, hbase + slot + 24);
        // virtual self edge at index cnt; padding -> zero row n
        int i0 = (slot      < cnt) ? s0 : ((slot      == cnt) ? v : n);
        int i1 = (slot + 8  < cnt) ? s1 : ((slot + 8  == cnt) ? v : n);
        int i2 = (slot + 16 < cnt) ? s2 : ((slot + 16 == cnt) ? v : n);
        int i3 = (slot + 24 < cnt) ? s3 : ((slot + 24 == cnt) ? v : n);
        uint2 w0 = *(const uint2*)(xd + (size_t)i0 * 8 + q * 2);
        uint2 w1 = *(const uint2*)(xd + (size_t)i1 * 8 + q * 2);
        uint2 w2 = *(const uint2*)(xd + (size_t)i2 * 8 + q * 2);
        uint2 w3 = *(const uint2*)(xd + (size_t)i3 * 8 + q * 2);
        #define ACC8(W) { a0 += fp8_lo(W.x); a1 += fp8_hi(W.x); \
                          a2 += fp8_lo(W.y); a3 += fp8_hi(W.y); }
        ACC8(w0) ACC8(w1) ACC8(w2) ACC8(w3)
        for (int k = slot + 32; k <= cnt; k += 8) {  // rare deg > 32 (incl. self)
            int s = (k < cnt) ? cp[k] : v;
            uint2 wr = *(const uint2*)(xd + (size_t)s * 8 + q * 2);
            ACC8(wr)
        }
        #undef ACC8
    }
    #pragma unroll
    for (int off = 4; off < 32; off <<= 1) {   // butterfly across slots (packed adds)
        a0 += shflx(a0, off);
        a1 += shflx(a1, off);
        a2 += shflx(a2, off);
        a3 += shflx(a3, off);
    }
    if (slot == 0) {   // 4 lanes per node-half hold channels q*8..q*8+7
        float* sp = &sums[wv * 2 + half][q * 8];
        sp[0] = a0[0]; sp[1] = a0[1]; sp[2] = a1[0]; sp[3] = a1[1];
        sp[4] = a2[0]; sp[5] = a2[1]; sp[6] = a3[0]; sp[7] = a3[1];
    }
    __syncthreads();
    // matmul1 + tanh: 128 threads = 8 nodes x 16 thr, 2 channels each
    if (t < 128) {
        int nl = t >> 4, c2 = (t & 15) * 2;
        int v1 = blockIdx.x * 8 + nl;
        float di = (v1 < n) ? dinv[v1] : 0.f;
        float s0 = 0.f, s1 = 0.f;
        #pragma unroll
        for (int k = 0; k < F_IN; ++k) {
            float sk = sums[nl][k];
            float2 wk = *(const float2*)&W1s[k * F_HID + c2];
            s0 += sk * wk.x;
            s1 += sk * wk.y;
        }
        hb[nl][c2]     = ftanh(s0 * di + b1[c2]);
        hb[nl][c2 + 1] = ftanh(s1 * di + b1[c2 + 1]);
    }
    __syncthreads();
    // matmul2: 32 threads = 8 nodes x 4 thr, 4 channels each -> fp8 pack direct
    if (t < 32) {
        int nl = t >> 2, c4 = (t & 3) * 4;
        int v2 = blockIdx.x * 8 + nl;
        float s0 = 0.f, s1 = 0.f, s2 = 0.f, s3 = 0.f;
        #pragma unroll
        for (int k = 0; k < F_HID; ++k) {
            float hk = hb[nl][k];
            float4 wk = *(const float4*)&W2s[k * F_OUT + c4];
            s0 += hk * wk.x; s1 += hk * wk.y;
            s2 += hk * wk.z; s3 += hk * wk.w;
        }
        if (v2 < n) {
            float di = dinv[v2];
            g2[(size_t)v2 * 4 + (c4 >> 2)] =
                pack_fp8x4(s0 * di, s1 * di, s2 * di, s3 * di);
        }
    }
}

// ---- agg2: fp8 gather (coalesced csr + virtual self edge); bias + log_softmax ----
__launch_bounds__(256)
__global__ void k_agg2(const uint32_t* __restrict__ g2, const int* __restrict__ csr,
                       const int* __restrict__ off_g,
                       const float* __restrict__ dinv, const float* __restrict__ b2,
                       float* __restrict__ out_h, float* __restrict__ out_ls, int n) {
    int t = threadIdx.x, wv = t >> 6, lane = t & 63;
    int half = lane >> 5, l = lane & 31;
    int v = blockIdx.x * 8 + wv * 2 + half;
    bool act = v < n;
    int q = l & 3, slot = l >> 2;  // 8 slots x 4 lanes x 4B per 16B row
    floatx2 b0 = {0.f, 0.f}, b1v = {0.f, 0.f};
    if (act) {
        int start = off_g[v], cnt = off_g[v + 1] - start;
        const int* cp = csr + start;
        int cl = cp[l];  // coalesced csr load (padded)
        int hbase = lane & 32;
        int s0 = __shfl(cl, hbase + slot);
        int s1 = __shfl(cl, hbase + slot + 8);
        int s2 = __shfl(cl, hbase + slot + 16);
        int s3 = __shfl(cl, hbase + slot + 24);
        int i0 = (slot      < cnt) ? s0 : ((slot      == cnt) ? v : n);
        int i1 = (slot + 8  < cnt) ? s1 : ((slot + 8  == cnt) ? v : n);
        int i2 = (slot + 16 < cnt) ? s2 : ((slot + 16 == cnt) ? v : n);
        int i3 = (slot + 24 < cnt) ? s3 : ((slot + 24 == cnt) ? v : n);
        uint32_t w0 = g2[(size_t)i0 * 4 + q];
        uint32_t w1 = g2[(size_t)i1 * 4 + q];
        uint32_t w2 = g2[(size_t)i2 * 4 + q];
        uint32_t w3 = g2[(size_t)i3 * 4 + q];
        #define ACC4(W) { b0 += fp8_lo(W); b1v += fp8_hi(W); }
        ACC4(w0) ACC4(w1) ACC4(w2) ACC4(w3)
        for (int k = slot + 32; k <= cnt; k += 8) {
            int s = (k < cnt) ? cp[k] : v;
            uint32_t wr = g2[(size_t)s * 4 + q];
            ACC4(wr)
        }
        #undef ACC4
    }
    #pragma unroll
    for (int off = 4; off < 32; off <<= 1) {
        b0 += shflx(b0, off);
        b1v += shflx(b1v, off);
    }
    if (l < 16) {
        int ch = l;
        int src = (lane & 32) + (ch >> 2);  // lane with q == ch>>2
        float a0 = __shfl(b0[0], src), a1 = __shfl(b0[1], src);
        float a2 = __shfl(b1v[0], src), a3 = __shfl(b1v[1], src);
        float f = (ch & 2) ? ((ch & 1) ? a3 : a2) : ((ch & 1) ? a1 : a0);
        float di = act ? dinv[v] : 0.f;
        float val = f * di + b2[ch];
        float m = val;
        m = fmaxf(m, __shfl_xor(m, 1));
        m = fmaxf(m, __shfl_xor(m, 2));
        m = fmaxf(m, __shfl_xor(m, 4));
        m = fmaxf(m, __shfl_xor(m, 8));
        float S = fexp(val - m);
        S += __shfl_xor(S, 1);
        S += __shfl_xor(S, 2);
        S += __shfl_xor(S, 4);
        S += __shfl_xor(S, 8);
        float L = __builtin_amdgcn_logf(S) * 0.69314718056f + m;
        if (act) {
            out_h[(size_t)v * F_OUT + ch]  = val;
            out_ls[(size_t)v * F_OUT + ch] = val - L;
        }
    }
}

static inline size_t align16(size_t x) { return (x + 15) & ~(size_t)15; }

extern "C" void kernel_launch(void* const* d_in, const int* in_sizes, int n_in,
                              void* d_out, int out_size, void* d_ws, size_t ws_size,
                              hipStream_t stream) {
    const float* x  = (const float*)d_in[0];
    const int*   ei = (const int*)d_in[1];   // [2,E]: [0:E]=src, [E:2E]=dst
    const float* W1 = (const float*)d_in[2];
    const float* b1 = (const float*)d_in[3];
    const float* W2 = (const float*)d_in[4];
    const float* b2 = (const float*)d_in[5];

    int n  = in_sizes[0] / F_IN;
    int ne = in_sizes[1] / 2;
    int nb = (n + NPB - 1) / NPB;
    int chunk = (((ne + BH - 1) / BH) + 3) & ~3;  // multiple of 4 for int4 loads

    float* out_h  = (float*)d_out;
    float* out_ls = out_h + (size_t)n * F_OUT;

    char* p = (char*)d_ws;
    float*    dinv     = (float*)p;    p += align16((size_t)n * sizeof(float));
    int*      totalG   = (int*)p;      p += align16(MAXNB * sizeof(int));
    int*      boff     = (int*)p;      p += align16((MAXNB + 4) * sizeof(int));
    int*      off_g    = (int*)p;      p += align16(((size_t)n + 4) * sizeof(int));
    int*      hist_mat = (int*)p;      p += align16((size_t)BH * nb * sizeof(int));
    int*      off_mat  = (int*)p;      p += align16((size_t)BH * nb * sizeof(int));
    uint32_t* ebuf     = (uint32_t*)p; p += align16((size_t)ne * sizeof(uint32_t));
    int*      csr      = (int*)p;      p += align16(((size_t)ne + 32) * sizeof(int));
    uint32_t* xd       = (uint32_t*)p; p += align16(((size_t)n + 1) * 8 * sizeof(uint32_t));
    uint32_t* g2       = (uint32_t*)p; p += align16(((size_t)n + 1) * 4 * sizeof(uint32_t));

    k_hist   <<<BH, 512, 0, stream>>>(ei, ne, chunk, nb, hist_mat);
    k_colscan<<<nb, 64, 0, stream>>>(hist_mat, off_mat, totalG, nb);
    k_fillc  <<<BH, 512, 0, stream>>>(ei, ne, chunk, nb, off_mat, totalG, boff, ebuf);
    k_pass2  <<<nb, 256, 0, stream>>>(ebuf, boff, x, csr, off_g, dinv, xd, n, nb);

    k_agg1   <<<(n + 7) / 8, 256, 0, stream>>>(xd, csr, off_g, dinv, b1, W1, W2, g2, n);
    k_agg2   <<<(n + 7) / 8, 256, 0, stream>>>(g2, csr, off_g, dinv, b2, out_h, out_ls, n);
}

// Round 18
// 96.898 us; speedup vs baseline: 1.0193x; 1.0193x over previous
//
#include <hip/hip_runtime.h>
#include <hip/hip_bf16.h>
#include <hip/hip_fp16.h>
#include <math.h>
#include <stdint.h>

#define F_IN  32
#define F_HID 32
#define F_OUT 16
#define NPB     256    // nodes per bucket
#define LOG_NPB 8
#define MAXNB   512    // supports n <= 131072
#define BH      512    // histogram/fill blocks

typedef float floatx2 __attribute__((ext_vector_type(2)));

__device__ inline floatx2 fp8_lo(uint32_t w) {   // 2 fp8 (bytes 0,1) -> 2 f32
    return __builtin_amdgcn_cvt_pk_f32_fp8(w, false);
}
__device__ inline floatx2 fp8_hi(uint32_t w) {   // 2 fp8 (bytes 2,3) -> 2 f32
    return __builtin_amdgcn_cvt_pk_f32_fp8(w, true);
}
__device__ inline uint32_t pack_fp8x4(float a, float b, float c, float d) {
    uint32_t u = __builtin_amdgcn_cvt_pk_fp8_f32(a, b, 0u, false);
    u = __builtin_amdgcn_cvt_pk_fp8_f32(c, d, u, true);
    return u;
}
__device__ inline floatx2 shflx(floatx2 v, int off) {
    floatx2 r;
    r[0] = __shfl_xor(v[0], off);
    r[1] = __shfl_xor(v[1], off);
    return r;
}

__device__ inline float fexp(float x) {           // e^x
    return __builtin_amdgcn_exp2f(x * 1.44269504089f);
}
__device__ inline float ftanh(float x) {          // tanh via exp2+rcp
    x = fminf(fmaxf(x, -15.f), 15.f);
    float t = __builtin_amdgcn_exp2f(x * 2.88539008178f);  // e^(2x)
    return (t - 1.0f) * __builtin_amdgcn_rcpf(t + 1.0f);
}

// ---- pass A: per-block bucket histogram, 8 replicated sub-hists ----
__launch_bounds__(512)
__global__ void k_hist(const int* __restrict__ ei, int ne, int chunk, int nb,
                       int* __restrict__ hist_mat) {
    __shared__ int hist[8][MAXNB];
    int t = threadIdx.x, b = blockIdx.x;
    int rep = t >> 6;  // per-wave sub-hist
    for (int i = t; i < 8 * MAXNB; i += 512) ((int*)hist)[i] = 0;
    __syncthreads();
    long s = (long)b * chunk;
    long e = s + chunk; if (e > ne) e = ne;
    const int* dstp = ei + ne;
    long i = s + (long)t * 4;
    for (; i + 4 <= e; i += 2048) {
        int4 d = *(const int4*)(dstp + i);
        atomicAdd(&hist[rep][d.x >> LOG_NPB], 1);
        atomicAdd(&hist[rep][d.y >> LOG_NPB], 1);
        atomicAdd(&hist[rep][d.z >> LOG_NPB], 1);
        atomicAdd(&hist[rep][d.w >> LOG_NPB], 1);
    }
    if (i < e)
        for (long j = i; j < e; ++j) atomicAdd(&hist[rep][dstp[j] >> LOG_NPB], 1);
    __syncthreads();
    for (int k = t; k < nb; k += 512) {
        int v = 0;
        #pragma unroll
        for (int r = 0; r < 8; ++r) v += hist[r][k];
        hist_mat[(size_t)b * nb + k] = v;
    }
}

// ---- column scan (wave per column): off_mat[b][k] = col-exclusive prefix ----
__launch_bounds__(64)
__global__ void k_colscan(const int* __restrict__ hist_mat, int* __restrict__ off_mat,
                          int* __restrict__ totalG, int nb) {
    int k = blockIdx.x;
    if (k >= nb) return;
    int lane = threadIdx.x;
    int run = 0;
    #pragma unroll
    for (int c = 0; c < BH; c += 64) {
        size_t idx = (size_t)(c + lane) * nb + k;
        int v = hist_mat[idx];
        int inc = v;
        #pragma unroll
        for (int o = 1; o < 64; o <<= 1) {
            int u = __shfl_up(inc, o);
            if (lane >= o) inc += u;
        }
        off_mat[idx] = run + inc - v;
        run += __shfl(inc, 63);
    }
    if (lane == 0) totalG[k] = run;
}

// ---- pass C: in-block boff scan + place edges via LDS cursors ----
__launch_bounds__(512)
__global__ void k_fillc(const int* __restrict__ ei, int ne, int chunk, int nb,
                        const int* __restrict__ off_mat, const int* __restrict__ totalG,
                        int* __restrict__ boff, uint32_t* __restrict__ ebuf) {
    __shared__ int cur[MAXNB];
    __shared__ int sc[512];
    int t = threadIdx.x, b = blockIdx.x;
    int tv = (t < nb) ? totalG[t] : 0;
    sc[t] = tv; __syncthreads();
    for (int o = 1; o < 512; o <<= 1) {
        int u = (t >= o) ? sc[t - o] : 0;
        __syncthreads();
        sc[t] += u;
        __syncthreads();
    }
    int myboff = sc[t] - tv;  // exclusive prefix of totalG at bucket t
    if (t < nb) cur[t] = off_mat[(size_t)b * nb + t] + myboff;
    if (b == 0) {  // publish boff for k_pass2
        if (t < nb) boff[t] = myboff;
        if (t == 0) boff[nb] = ne;
    }
    __syncthreads();
    long s = (long)b * chunk;
    long e = s + chunk; if (e > ne) e = ne;
    const int* srcp = ei;
    const int* dstp = ei + ne;
    long i = s + (long)t * 4;
    for (; i + 4 <= e; i += 2048) {
        int4 sv = *(const int4*)(srcp + i);
        int4 dv = *(const int4*)(dstp + i);
        int p0 = atomicAdd(&cur[dv.x >> LOG_NPB], 1);
        ebuf[p0] = (uint32_t)sv.x | ((uint32_t)(dv.x & (NPB - 1)) << 17);
        int p1 = atomicAdd(&cur[dv.y >> LOG_NPB], 1);
        ebuf[p1] = (uint32_t)sv.y | ((uint32_t)(dv.y & (NPB - 1)) << 17);
        int p2 = atomicAdd(&cur[dv.z >> LOG_NPB], 1);
        ebuf[p2] = (uint32_t)sv.z | ((uint32_t)(dv.z & (NPB - 1)) << 17);
        int p3 = atomicAdd(&cur[dv.w >> LOG_NPB], 1);
        ebuf[p3] = (uint32_t)sv.w | ((uint32_t)(dv.w & (NPB - 1)) << 17);
    }
    if (i < e) {
        for (long j = i; j < e; ++j) {
            int sn = srcp[j], dn = dstp[j];
            int p = atomicAdd(&cur[dn >> LOG_NPB], 1);
            ebuf[p] = (uint32_t)sn | ((uint32_t)(dn & (NPB - 1)) << 17);
        }
    }
}

// ---- pass 2: within-bucket sort -> csr + off_g + dinv + xd = x*dinv (fp8 x4) ----
__launch_bounds__(256)
__global__ void k_pass2(const uint32_t* __restrict__ ebuf, const int* __restrict__ boff,
                        const float* __restrict__ x,
                        int* __restrict__ csr, int* __restrict__ off_g,
                        float* __restrict__ dinv, uint32_t* __restrict__ xd,
                        int n, int nb) {
    __shared__ int hist[NPB], scn[NPB], cur[NPB];
    __shared__ float sdi[NPB];
    int b = blockIdx.x, t = threadIdx.x;
    int base = boff[b], end = boff[b + 1];
    int v0 = b << LOG_NPB;
    hist[t] = 0;
    __syncthreads();
    for (int i = base + t; i < end; i += 256)
        atomicAdd(&hist[(ebuf[i] >> 17) & (NPB - 1)], 1);
    __syncthreads();
    int val = hist[t];
    scn[t] = val; __syncthreads();
    for (int o = 1; o < 256; o <<= 1) {
        int u = (t >= o) ? scn[t - o] : 0;
        __syncthreads();
        scn[t] += u;
        __syncthreads();
    }
    int excl = scn[t] - val + base;
    cur[t] = excl;
    int v = v0 + t;
    float d = 0.f;
    if (v < n) {
        off_g[v] = excl;
        d = rsqrtf((float)(val + 1));  // +1 self-loop
        dinv[v] = d;
    }
    sdi[t] = d;
    if (b == nb - 1 && t == 0) off_g[n] = end;
    if (b == nb - 1 && t < 8) xd[(size_t)n * 8 + t] = 0u;  // zero row for padding
    __syncthreads();
    for (int i = base + t; i < end; i += 256) {
        uint32_t r = ebuf[i];
        int slot = atomicAdd(&cur[(r >> 17) & (NPB - 1)], 1);
        csr[slot] = (int)(r & 0x1FFFF);
    }
    // xd = x * dinv, packed fp8 e4m3 (8 words/node = 32 ch)
    for (int i = t; i < NPB * 8; i += 256) {
        int nl = i >> 3, wp = i & 7;
        int vv = v0 + nl;
        if (vv < n) {
            float4 xx = *(const float4*)(x + (size_t)vv * F_IN + 4 * wp);
            float di = sdi[nl];
            xd[(size_t)vv * 8 + wp] =
                pack_fp8x4(xx.x * di, xx.y * di, xx.z * di, xx.w * di);
        }
    }
}

// ---- agg1: fp8 gather (4-deep), packed-f32 accumulate, W1->tanh->W2 -> g2 ----
__launch_bounds__(256)
__global__ void k_agg1(const uint32_t* __restrict__ xd, const int* __restrict__ csr,
                       const int* __restrict__ off_g,
                       const float* __restrict__ dinv, const float* __restrict__ b1,
                       const float* __restrict__ W1, const float* __restrict__ W2,
                       uint32_t* __restrict__ g2, int n) {
    __shared__ float W1s[F_IN * F_HID];
    __shared__ float W2s[F_HID * F_OUT];
    __shared__ float sums[8][F_IN + 1];
    __shared__ float hb[8][F_HID + 1];
    int t = threadIdx.x, wv = t >> 6, lane = t & 63;
    ((float4*)W1s)[t] = ((const float4*)W1)[t];               // 1024 floats
    if (t < 128) ((float4*)W2s)[t] = ((const float4*)W2)[t];  // 512 floats
    if (blockIdx.x == 0 && t < 4) g2[(size_t)n * 4 + t] = 0u; // zero row for agg2
    int half = lane >> 5, l = lane & 31;
    int v = blockIdx.x * 8 + wv * 2 + half;
    bool act = v < n;
    int q = l & 3, slot = l >> 2;  // 8 edge slots x 4 lanes x 8B per 32B row
    floatx2 a0 = {0.f, 0.f}, a1 = {0.f, 0.f}, a2 = {0.f, 0.f}, a3 = {0.f, 0.f};
    if (act) {
        int start = off_g[v], cnt = off_g[v + 1] - start;
        const int* cp = csr + start;
        int i0 = (slot      < cnt) ? cp[slot]      : n;
        int i1 = (slot + 8  < cnt) ? cp[slot + 8]  : n;
        int i2 = (slot + 16 < cnt) ? cp[slot + 16] : n;
        int i3 = (slot + 24 < cnt) ? cp[slot + 24] : n;
        int iS = (slot == 0) ? v : n;  // self-loop in slot 0
        uint2 w0 = *(const uint2*)(xd + (size_t)i0 * 8 + q * 2);
        uint2 w1 = *(const uint2*)(xd + (size_t)i1 * 8 + q * 2);
        uint2 w2 = *(const uint2*)(xd + (size_t)i2 * 8 + q * 2);
        uint2 w3 = *(const uint2*)(xd + (size_t)i3 * 8 + q * 2);
        uint2 wS = *(const uint2*)(xd + (size_t)iS * 8 + q * 2);
        #define ACC8(W) { a0 += fp8_lo(W.x); a1 += fp8_hi(W.x); \
                          a2 += fp8_lo(W.y); a3 += fp8_hi(W.y); }
        ACC8(w0) ACC8(w1) ACC8(w2) ACC8(w3) ACC8(wS)
        for (int k = slot + 32; k < cnt; k += 8) {  // rare deg > 32
            int s = cp[k];
            uint2 wr = *(const uint2*)(xd + (size_t)s * 8 + q * 2);
            ACC8(wr)
        }
        #undef ACC8
    }
    #pragma unroll
    for (int off = 4; off < 32; off <<= 1) {   // butterfly across slots (packed adds)
        a0 += shflx(a0, off);
        a1 += shflx(a1, off);
        a2 += shflx(a2, off);
        a3 += shflx(a3, off);
    }
    if (slot == 0) {   // 4 lanes per node-half hold channels q*8..q*8+7
        float* sp = &sums[wv * 2 + half][q * 8];
        sp[0] = a0[0]; sp[1] = a0[1]; sp[2] = a1[0]; sp[3] = a1[1];
        sp[4] = a2[0]; sp[5] = a2[1]; sp[6] = a3[0]; sp[7] = a3[1];
    }
    __syncthreads();
    // matmul1 + tanh: 128 threads = 8 nodes x 16 thr, 2 channels each
    if (t < 128) {
        int nl = t >> 4, c2 = (t & 15) * 2;
        int v1 = blockIdx.x * 8 + nl;
        float di = (v1 < n) ? dinv[v1] : 0.f;
        float s0 = 0.f, s1 = 0.f;
        #pragma unroll
        for (int k = 0; k < F_IN; ++k) {
            float sk = sums[nl][k];
            float2 wk = *(const float2*)&W1s[k * F_HID + c2];
            s0 += sk * wk.x;
            s1 += sk * wk.y;
        }
        hb[nl][c2]     = ftanh(s0 * di + b1[c2]);
        hb[nl][c2 + 1] = ftanh(s1 * di + b1[c2 + 1]);
    }
    __syncthreads();
    // matmul2: 32 threads = 8 nodes x 4 thr, 4 channels each -> fp8 pack direct
    if (t < 32) {
        int nl = t >> 2, c4 = (t & 3) * 4;
        int v2 = blockIdx.x * 8 + nl;
        float s0 = 0.f, s1 = 0.f, s2 = 0.f, s3 = 0.f;
        #pragma unroll
        for (int k = 0; k < F_HID; ++k) {
            float hk = hb[nl][k];
            float4 wk = *(const float4*)&W2s[k * F_OUT + c4];
            s0 += hk * wk.x; s1 += hk * wk.y;
            s2 += hk * wk.z; s3 += hk * wk.w;
        }
        if (v2 < n) {
            float di = dinv[v2];
            g2[(size_t)v2 * 4 + (c4 >> 2)] =
                pack_fp8x4(s0 * di, s1 * di, s2 * di, s3 * di);
        }
    }
}

// ---- agg2: fp8 gather (4-deep), packed-f32 accumulate; bias + log_softmax ----
__launch_bounds__(256)
__global__ void k_agg2(const uint32_t* __restrict__ g2, const int* __restrict__ csr,
                       const int* __restrict__ off_g,
                       const float* __restrict__ dinv, const float* __restrict__ b2,
                       float* __restrict__ out_h, float* __restrict__ out_ls, int n) {
    int t = threadIdx.x, wv = t >> 6, lane = t & 63;
    int half = lane >> 5, l = lane & 31;
    int v = blockIdx.x * 8 + wv * 2 + half;
    bool act = v < n;
    int q = l & 3, slot = l >> 2;  // 8 slots x 4 lanes x 4B per 16B row
    floatx2 b0 = {0.f, 0.f}, b1v = {0.f, 0.f};
    if (act) {
        int start = off_g[v], cnt = off_g[v + 1] - start;
        const int* cp = csr + start;
        int i0 = (slot      < cnt) ? cp[slot]      : n;
        int i1 = (slot + 8  < cnt) ? cp[slot + 8]  : n;
        int i2 = (slot + 16 < cnt) ? cp[slot + 16] : n;
        int i3 = (slot + 24 < cnt) ? cp[slot + 24] : n;
        int iS = (slot == 0) ? v : n;
        uint32_t w0 = g2[(size_t)i0 * 4 + q];
        uint32_t w1 = g2[(size_t)i1 * 4 + q];
        uint32_t w2 = g2[(size_t)i2 * 4 + q];
        uint32_t w3 = g2[(size_t)i3 * 4 + q];
        uint32_t wS = g2[(size_t)iS * 4 + q];
        #define ACC4(W) { b0 += fp8_lo(W); b1v += fp8_hi(W); }
        ACC4(w0) ACC4(w1) ACC4(w2) ACC4(w3) ACC4(wS)
        for (int k = slot + 32; k < cnt; k += 8) {
            uint32_t wr = g2[(size_t)cp[k] * 4 + q];
            ACC4(wr)
        }
        #undef ACC4
    }
    #pragma unroll
    for (int off = 4; off < 32; off <<= 1) {
        b0 += shflx(b0, off);
        b1v += shflx(b1v, off);
    }
    if (l < 16) {
        int ch = l;
        int src = (lane & 32) + (ch >> 2);  // lane with q == ch>>2
        float a0 = __shfl(b0[0], src), a1 = __shfl(b0[1], src);
        float a2 = __shfl(b1v[0], src), a3 = __shfl(b1v[1], src);
        float f = (ch & 2) ? ((ch & 1) ? a3 : a2) : ((ch & 1) ? a1 : a0);
        float di = act ? dinv[v] : 0.f;
        float val = f * di + b2[ch];
        float m = val;
        m = fmaxf(m, __shfl_xor(m, 1));
        m = fmaxf(m, __shfl_xor(m, 2));
        m = fmaxf(m, __shfl_xor(m, 4));
        m = fmaxf(m, __shfl_xor(m, 8));
        float S = fexp(val - m);
        S += __shfl_xor(S, 1);
        S += __shfl_xor(S, 2);
        S += __shfl_xor(S, 4);
        S += __shfl_xor(S, 8);
        float L = __builtin_amdgcn_logf(S) * 0.69314718056f + m;
        if (act) {
            out_h[(size_t)v * F_OUT + ch]  = val;
            out_ls[(size_t)v * F_OUT + ch] = val - L;
        }
    }
}

static inline size_t align16(size_t x) { return (x + 15) & ~(size_t)15; }

extern "C" void kernel_launch(void* const* d_in, const int* in_sizes, int n_in,
                              void* d_out, int out_size, void* d_ws, size_t ws_size,
                              hipStream_t stream) {
    const float* x  = (const float*)d_in[0];
    const int*   ei = (const int*)d_in[1];   // [2,E]: [0:E]=src, [E:2E]=dst
    const float* W1 = (const float*)d_in[2];
    const float* b1 = (const float*)d_in[3];
    const float* W2 = (const float*)d_in[4];
    const float* b2 = (const float*)d_in[5];

    int n  = in_sizes[0] / F_IN;
    int ne = in_sizes[1] / 2;
    int nb = (n + NPB - 1) / NPB;
    int chunk = (((ne + BH - 1) / BH) + 3) & ~3;  // multiple of 4 for int4 loads

    float* out_h  = (float*)d_out;
    float* out_ls = out_h + (size_t)n * F_OUT;

    char* p = (char*)d_ws;
    float*    dinv     = (float*)p;    p += align16((size_t)n * sizeof(float));
    int*      totalG   = (int*)p;      p += align16(MAXNB * sizeof(int));
    int*      boff     = (int*)p;      p += align16((MAXNB + 4) * sizeof(int));
    int*      off_g    = (int*)p;      p += align16(((size_t)n + 4) * sizeof(int));
    int*      hist_mat = (int*)p;      p += align16((size_t)BH * nb * sizeof(int));
    int*      off_mat  = (int*)p;      p += align16((size_t)BH * nb * sizeof(int));
    uint32_t* ebuf     = (uint32_t*)p; p += align16((size_t)ne * sizeof(uint32_t));
    int*      csr      = (int*)p;      p += align16((size_t)ne * sizeof(int));
    uint32_t* xd       = (uint32_t*)p; p += align16(((size_t)n + 1) * 8 * sizeof(uint32_t));
    uint32_t* g2       = (uint32_t*)p; p += align16(((size_t)n + 1) * 4 * sizeof(uint32_t));

    k_hist   <<<BH, 512, 0, stream>>>(ei, ne, chunk, nb, hist_mat);
    k_colscan<<<nb, 64, 0, stream>>>(hist_mat, off_mat, totalG, nb);
    k_fillc  <<<BH, 512, 0, stream>>>(ei, ne, chunk, nb, off_mat, totalG, boff, ebuf);
    k_pass2  <<<nb, 256, 0, stream>>>(ebuf, boff, x, csr, off_g, dinv, xd, n, nb);

    k_agg1   <<<(n + 7) / 8, 256, 0, stream>>>(xd, csr, off_g, dinv, b1, W1, W2, g2, n);
    k_agg2   <<<(n + 7) / 8, 256, 0, stream>>>(g2, csr, off_g, dinv, b2, out_h, out_ls, n);
}